// Round 10
// baseline (111.186 us; speedup 1.0000x reference)
//
#include <hip/hip_runtime.h>
#include <math.h>

#define Hd 128
#define Rr 3
#define Ll 4
#define NPW 32   // nodes (M-rows) per wave = 2 M-tiles of 16
#define NW  4    // waves per block

typedef float f32x4 __attribute__((ext_vector_type(4)));
typedef short s16x8 __attribute__((ext_vector_type(8)));

__device__ __forceinline__ unsigned short f2bf(float f){
    unsigned u = __float_as_uint(f);
    return (unsigned short)((u + 0x7FFFu + ((u >> 16) & 1u)) >> 16);
}
// convert 8 consecutive f32 -> bf16 A-fragment
__device__ __forceinline__ s16x8 cvt8(const float* p){
    float4 a = *(const float4*)p;
    float4 b = *(const float4*)(p + 4);
    float v[8] = {a.x, a.y, a.z, a.w, b.x, b.y, b.z, b.w};
    s16x8 r;
    #pragma unroll
    for (int j = 0; j < 8; ++j) r[j] = (short)f2bf(v[j]);
    return r;
}
__device__ __forceinline__ int lower_bound_i32(const int* __restrict__ a, int n, int key){
    int lo = 0, hi = n;
    while (lo < hi){
        int mid = (lo + hi) >> 1;
        if (a[mid] < key) lo = mid + 1; else hi = mid;
    }
    return lo;
}

// async global->LDS, 16B per lane; LDS dest = uniform base + lane*16
__device__ __forceinline__ void gload_lds16(const unsigned short* g, unsigned short* l){
    __builtin_amdgcn_global_load_lds(
        (const __attribute__((address_space(1))) void*)g,
        (__attribute__((address_space(3))) void*)l, 16, 0, 0);
}

// ---- McT = out_w @ wv (folded), bc = out_w @ bv + out_b  (verified r1-r9) ----
__global__ void fold_proj_kernel(const float* __restrict__ in_proj_w,
                                 const float* __restrict__ in_proj_b,
                                 const float* __restrict__ out_w,
                                 const float* __restrict__ out_b,
                                 float* __restrict__ McT,
                                 float* __restrict__ bc)
{
    const int i = blockIdx.x;   // k index
    const int j = threadIdx.x;  // n index
    float acc = 0.f;
    for (int k = 0; k < Hd; ++k)
        acc = fmaf(out_w[j * Hd + k], in_proj_w[(2 * Hd + k) * Hd + i], acc);
    McT[i * Hd + j] = acc;
    if (i == 0){
        float b = out_b[j];
        for (int k = 0; k < Hd; ++k)
            b = fmaf(out_w[j * Hd + k], in_proj_b[2 * Hd + k], b);
        bc[j] = b;
    }
}

// ---- quantize weights to bf16 MFMA B-fragments (verified r4-r9) ----
// frag elem j of lane l at (mat,kc,nc):  W[kc*32 + (l>>4)*8 + j][nc*16 + (l&15)]
__global__ void pack_kernel(const float* __restrict__ r_whh, const float* __restrict__ u_whh,
                            const float* __restrict__ r_wxh, const float* __restrict__ u_wxh,
                            const float* __restrict__ c_whh, const float* __restrict__ c_wxh,
                            const float* __restrict__ McT,
                            unsigned short* __restrict__ whi)
{
    const int mat  = blockIdx.y;   // 0..6
    const int tile = blockIdx.x;   // 0..31 : kc = tile>>3, nc = tile&7
    const int l    = threadIdx.x;  // 0..63
    const float* W;
    switch (mat){
        case 0: W = r_whh; break;  case 1: W = u_whh; break;
        case 2: W = r_wxh; break;  case 3: W = u_wxh; break;
        case 4: W = c_whh; break;  case 5: W = c_wxh; break;
        default: W = McT;
    }
    const int kc = tile >> 3, nc = tile & 7;
    const int kbase = kc * 32 + (l >> 4) * 8;
    const int n = nc * 16 + (l & 15);
    const size_t obase = ((size_t)(mat * 32 + tile) * 64 + l) * 8;
    #pragma unroll
    for (int j = 0; j < 8; ++j)
        whi[obase + j] = f2bf(W[(kbase + j) * Hd + n]);
}

// B-frag read from current LDS weight buffer (ds_read_b128, contiguous per wave)
#define BF_LDS(kc, nc) (*(const s16x8*)&WL[cur][(((kc) * 8 + (nc)) * 64 + l) * 8])

#define MM1(acc, AH, BH)                                                  \
    acc = __builtin_amdgcn_mfma_f32_16x16x32_bf16(AH, BH, acc, 0, 0, 0);

__global__ __launch_bounds__(256, 1) void gru_mfma_kernel(
    const float* __restrict__ x_rank,
    const int* __restrict__ valid_idx, int nv,
    const float* __restrict__ r_b, const float* __restrict__ u_b, const float* __restrict__ c_b,
    const unsigned short* __restrict__ whi,
    const float* __restrict__ bc,
    float* __restrict__ out, int N)
{
    // double-buffered block-shared weight stage (2 x 32 KB)
    __shared__ __align__(16) unsigned short WL[2][16384];
    // per-wave multi-purpose scratch: rh -> z -> h' -> out (elementwise reuse)
    __shared__ __align__(16) float Sr_all[NW][NPW][132];
    __shared__ float bias_s[4][Hd];
    __shared__ int lo_all[NW][NPW];
    __shared__ int hi_all[NW][NPW];

    const int tid = threadIdx.x;
    const int wid = tid >> 6;
    const int l   = tid & 63;
    const int lr  = l & 15;
    const int lg  = l >> 4;
    const int n0  = (blockIdx.x * NW + wid) * NPW;

    float (*Sr)[132] = Sr_all[wid];
    int* loL = lo_all[wid];
    int* hiL = hi_all[wid];

    if (tid < Hd){
        bias_s[0][tid] = r_b[tid];
        bias_s[1][tid] = u_b[tid];
        bias_s[2][tid] = c_b[tid];
        bias_s[3][tid] = bc[tid];
    }

    // stage one 32KB matrix into buffer b: 32 chunks of 1KB, wave covers it*4+wid
    #define STAGE_MAT(mat, b)                                                    \
        {                                                                        \
            const unsigned short* msrc = whi + (size_t)(mat) * 16384;            \
            _Pragma("unroll")                                                    \
            for (int it = 0; it < 8; ++it){                                      \
                const int chunk = it * 4 + wid;                                  \
                gload_lds16(msrc + chunk * 512 + l * 8, &WL[b][chunk * 512]);    \
            }                                                                    \
        }

    // persistent register state (dual M-tile: mt=0 rows 0-15, mt=1 rows 16-31)
    f32x4 hD[2][8];           // h f32 in D-layout: row mt*16+lg*4+i, col nc*16+lr
    s16x8 ah[2][4];           // h A-frags bf16 (row mt*16+lr, k = kc*32+lg*8+j)
    #pragma unroll
    for (int mt = 0; mt < 2; ++mt){
        #pragma unroll
        for (int nc = 0; nc < 8; ++nc) hD[mt][nc] = (f32x4){0.f, 0.f, 0.f, 0.f};
        #pragma unroll
        for (int kc = 0; kc < 4; ++kc) ah[mt][kc] = (s16x8)0;
    }
    s16x8 xh[2][4], rhh[2][4];

    unsigned cur = 0;
    STAGE_MAT(0, 0);          // prologue: r_whh into buf0

    #pragma unroll 1
    for (int t = 0; t < Rr; ++t){
        // ---- output-row ranges (32 rows per wave) ----
        if (l < NPW){
            int n = n0 + l, lo = 0, hi = 0;
            if (n < N){
                int F = (n * Rr + t) * Ll;
                lo = lower_bound_i32(valid_idx, nv, F);
                hi = lower_bound_i32(valid_idx, nv, F + Ll);
            }
            loL[l] = lo; hiL[l] = hi;
        }

        // ---- x A-frags for both M-tiles (clamped; OOB rows never stored) ----
        #pragma unroll
        for (int mt = 0; mt < 2; ++mt){
            int nn = n0 + mt * 16 + lr; if (nn > N - 1) nn = N - 1;
            const float* xp = x_rank + ((size_t)nn * Rr + t) * Hd;
            #pragma unroll
            for (int kc = 0; kc < 4; ++kc)
                xh[mt][kc] = cvt8(xp + kc * 32 + lg * 8);
        }

        // ==== S1: [r_whh ready] issue r_wxh; accR = h @ r_whh ====
        __syncthreads();
        STAGE_MAT(2, cur ^ 1);
        f32x4 accR[2][8];
        #pragma unroll
        for (int nc = 0; nc < 8; ++nc){
            accR[0][nc] = (f32x4){0.f, 0.f, 0.f, 0.f};
            accR[1][nc] = (f32x4){0.f, 0.f, 0.f, 0.f};
            #pragma unroll
            for (int kc = 0; kc < 4; ++kc){
                s16x8 b = BF_LDS(kc, nc);
                MM1(accR[0][nc], ah[0][kc], b);
                MM1(accR[1][nc], ah[1][kc], b);
            }
            if ((nc & 3) == 3) __builtin_amdgcn_sched_barrier(0);
        }
        cur ^= 1;

        // ==== S2: [r_wxh ready] issue u_whh; accR += x @ r_wxh ; Sr = r*h ====
        __syncthreads();
        STAGE_MAT(1, cur ^ 1);
        #pragma unroll
        for (int nc = 0; nc < 8; ++nc){
            #pragma unroll
            for (int kc = 0; kc < 4; ++kc){
                s16x8 b = BF_LDS(kc, nc);
                MM1(accR[0][nc], xh[0][kc], b);
                MM1(accR[1][nc], xh[1][kc], b);
            }
            const float rbc = bias_s[0][nc * 16 + lr];
            #pragma unroll
            for (int mt = 0; mt < 2; ++mt)
                #pragma unroll
                for (int i = 0; i < 4; ++i){
                    float r = 1.f / (1.f + __expf(-(accR[mt][nc][i] + rbc)));
                    Sr[mt * 16 + lg * 4 + i][nc * 16 + lr] = r * hD[mt][nc][i];
                }
            if ((nc & 3) == 3) __builtin_amdgcn_sched_barrier(0);
        }
        cur ^= 1;

        // ==== S3: [u_whh ready] issue u_wxh; accZ = h @ u_whh  (ah dies after) ====
        __syncthreads();
        STAGE_MAT(3, cur ^ 1);
        f32x4 accZ[2][8];
        #pragma unroll
        for (int nc = 0; nc < 8; ++nc){
            accZ[0][nc] = (f32x4){0.f, 0.f, 0.f, 0.f};
            accZ[1][nc] = (f32x4){0.f, 0.f, 0.f, 0.f};
            #pragma unroll
            for (int kc = 0; kc < 4; ++kc){
                s16x8 b = BF_LDS(kc, nc);
                MM1(accZ[0][nc], ah[0][kc], b);
                MM1(accZ[1][nc], ah[1][kc], b);
            }
            if ((nc & 3) == 3) __builtin_amdgcn_sched_barrier(0);
        }
        cur ^= 1;

        // ==== S4: [u_wxh ready] issue c_whh; rhh frags from Sr (rh), then
        //          accZ += x @ u_wxh ; z = sigmoid -> Sr (overwrite rh) ====
        __syncthreads();
        STAGE_MAT(4, cur ^ 1);
        #pragma unroll
        for (int mt = 0; mt < 2; ++mt)
            #pragma unroll
            for (int kc = 0; kc < 4; ++kc)
                rhh[mt][kc] = cvt8(&Sr[mt * 16 + lr][kc * 32 + lg * 8]);
        __builtin_amdgcn_sched_barrier(0);
        #pragma unroll
        for (int nc = 0; nc < 8; ++nc){
            #pragma unroll
            for (int kc = 0; kc < 4; ++kc){
                s16x8 b = BF_LDS(kc, nc);
                MM1(accZ[0][nc], xh[0][kc], b);
                MM1(accZ[1][nc], xh[1][kc], b);
            }
            const float ubc = bias_s[1][nc * 16 + lr];
            #pragma unroll
            for (int mt = 0; mt < 2; ++mt)
                #pragma unroll
                for (int i = 0; i < 4; ++i){
                    float z = 1.f / (1.f + __expf(-(accZ[mt][nc][i] + ubc)));
                    Sr[mt * 16 + lg * 4 + i][nc * 16 + lr] = z;
                }
            if ((nc & 3) == 3) __builtin_amdgcn_sched_barrier(0);
        }
        cur ^= 1;

        // ==== S5: [c_whh ready] issue c_wxh; accC = (r*h) @ c_whh ====
        __syncthreads();
        STAGE_MAT(5, cur ^ 1);
        f32x4 accC[2][8];
        #pragma unroll
        for (int nc = 0; nc < 8; ++nc){
            accC[0][nc] = (f32x4){0.f, 0.f, 0.f, 0.f};
            accC[1][nc] = (f32x4){0.f, 0.f, 0.f, 0.f};
            #pragma unroll
            for (int kc = 0; kc < 4; ++kc){
                s16x8 b = BF_LDS(kc, nc);
                MM1(accC[0][nc], rhh[0][kc], b);
                MM1(accC[1][nc], rhh[1][kc], b);
            }
            if ((nc & 3) == 3) __builtin_amdgcn_sched_barrier(0);
        }
        cur ^= 1;

        // ==== S6: [c_wxh ready] issue McT; accC += x @ c_wxh ;
        //          h' = h + z*(tanh(accC+cb)-h) (z from Sr, in-place -> h') ====
        __syncthreads();
        STAGE_MAT(6, cur ^ 1);
        #pragma unroll
        for (int nc = 0; nc < 8; ++nc){
            #pragma unroll
            for (int kc = 0; kc < 4; ++kc){
                s16x8 b = BF_LDS(kc, nc);
                MM1(accC[0][nc], xh[0][kc], b);
                MM1(accC[1][nc], xh[1][kc], b);
            }
            const float cbc = bias_s[2][nc * 16 + lr];
            #pragma unroll
            for (int mt = 0; mt < 2; ++mt)
                #pragma unroll
                for (int i = 0; i < 4; ++i){
                    const int row = mt * 16 + lg * 4 + i, col = nc * 16 + lr;
                    float e = __expf(2.f * (accC[mt][nc][i] + cbc));
                    float c = 1.f - 2.f / (e + 1.f);   // tanh, saturates correctly
                    float z  = Sr[row][col];
                    float ho = hD[mt][nc][i];
                    float hn = ho + z * (c - ho);
                    hD[mt][nc][i] = hn;
                    Sr[row][col] = hn;
                }
            if ((nc & 3) == 3) __builtin_amdgcn_sched_barrier(0);
        }
        // h' A-frags: serve S7 now AND S1 of next t
        #pragma unroll
        for (int mt = 0; mt < 2; ++mt)
            #pragma unroll
            for (int kc = 0; kc < 4; ++kc)
                ah[mt][kc] = cvt8(&Sr[mt * 16 + lr][kc * 32 + lg * 8]);
        cur ^= 1;

        // ==== S7: [McT ready] issue r_whh (next t); out rows -> Sr; scatter ====
        __syncthreads();
        if (t < Rr - 1) STAGE_MAT(0, cur ^ 1);
        #pragma unroll
        for (int nc = 0; nc < 8; ++nc){
            f32x4 ao0 = (f32x4){0.f, 0.f, 0.f, 0.f};
            f32x4 ao1 = (f32x4){0.f, 0.f, 0.f, 0.f};
            #pragma unroll
            for (int kc = 0; kc < 4; ++kc){
                s16x8 b = BF_LDS(kc, nc);
                MM1(ao0, ah[0][kc], b);
                MM1(ao1, ah[1][kc], b);
            }
            const float obc = bias_s[3][nc * 16 + lr];
            #pragma unroll
            for (int i = 0; i < 4; ++i){
                Sr[lg * 4 + i][nc * 16 + lr]      = ao0[i] + obc;
                Sr[16 + lg * 4 + i][nc * 16 + lr] = ao1[i] + obc;
            }
            if ((nc & 3) == 3) __builtin_amdgcn_sched_barrier(0);
        }
        __builtin_amdgcn_sched_barrier(0);

        // epilogue: 32 lanes emit one full 512-B row; run replication via loL/hiL
        #pragma unroll
        for (int m = 0; m < 16; ++m){
            const int row = m * 2 + (l >> 5);
            const int c4  = (l & 31) * 4;
            const float4 v = *(const float4*)&Sr[row][c4];
            const int lo = loL[row], hi = hiL[row];
            for (int rr = lo; rr < hi; ++rr)
                *(float4*)(out + (size_t)rr * Hd + c4) = v;
        }
        cur ^= 1;
    }
    #undef STAGE_MAT
}

__global__ void he_order_kernel(const int* __restrict__ he_order,
                                float* __restrict__ out_tail, int nv)
{
    const int i = blockIdx.x * 256 + threadIdx.x;
    if (i < nv) out_tail[i] = (float)he_order[i];
}

extern "C" void kernel_launch(void* const* d_in, const int* in_sizes, int n_in,
                              void* d_out, int out_size, void* d_ws, size_t ws_size,
                              hipStream_t stream)
{
    const float* x_rank    = (const float*)d_in[0];
    // d_in[1] he_features, d_in[2] he_idx: dead (softmax over singleton axis == 1)
    const int*   valid_idx = (const int*)d_in[3];
    const int*   he_order  = (const int*)d_in[4];
    const float* r_whh = (const float*)d_in[5];
    const float* r_wxh = (const float*)d_in[6];
    const float* r_b   = (const float*)d_in[7];
    const float* u_whh = (const float*)d_in[8];
    const float* u_wxh = (const float*)d_in[9];
    const float* u_b   = (const float*)d_in[10];
    const float* c_whh = (const float*)d_in[11];
    const float* c_wxh = (const float*)d_in[12];
    const float* c_b   = (const float*)d_in[13];
    const float* in_proj_w = (const float*)d_in[14];
    const float* in_proj_b = (const float*)d_in[15];
    const float* out_w     = (const float*)d_in[16];
    const float* out_b     = (const float*)d_in[17];

    const int nv = in_sizes[3];
    const int N  = in_sizes[0] / (Rr * Hd);

    // workspace layout
    float* McT = (float*)d_ws;                         // 16384 f32
    float* bc  = McT + Hd * Hd;                        // 128 f32
    unsigned short* whi = (unsigned short*)(bc + Hd);  // 7*16384 u16

    float* out_f    = (float*)d_out;
    float* out_tail = out_f + (size_t)nv * Hd;

    fold_proj_kernel<<<Hd, Hd, 0, stream>>>(in_proj_w, in_proj_b, out_w, out_b, McT, bc);
    pack_kernel<<<dim3(32, 7), 64, 0, stream>>>(r_whh, u_whh, r_wxh, u_wxh, c_whh, c_wxh,
                                                McT, whi);

    const int nodes_per_block = NW * NPW;  // 128
    const int nblocks = (N + nodes_per_block - 1) / nodes_per_block;  // 235
    gru_mfma_kernel<<<nblocks, 256, 0, stream>>>(
        x_rank, valid_idx, nv, r_b, u_b, c_b, whi, bc, out_f, N);

    he_order_kernel<<<(nv + 255) / 256, 256, 0, stream>>>(he_order, out_tail, nv);
}